// Round 2
// baseline (334.646 us; speedup 1.0000x reference)
//
#include <hip/hip_runtime.h>

// RingAttention: out = softmax(Q K^T) V  (no scale), B=32 SQ=1024 SKV=8192 D=64, fp32 I/O.
// Strategy: fp16 MFMA (32x32x16), Q split hi+lo (error ~2e-3 in logits), S^T formulation
// so softmax is lane-local and P needs only shfl_xor(32) to become the PV A-operand.
// V staged transposed in LDS. 1 block/CU, double-buffered LDS, register prefetch.

#define NBATCH 32
#define SQL 1024
#define SKVL 8192
#define DH 64
#define BM 128                 // q rows per block (4 waves x 32)
#define BN 64                  // kv rows per tile
#define NT (SKVL / BN)         // 128 tiles
#define KSTR 72                // K lds row stride in halfs (pad: bank-clean, 16B-aligned rows)
#define VSTR 72                // V^T lds row stride in halfs

typedef _Float16 half8 __attribute__((ext_vector_type(8)));
typedef __fp16 fp16x2 __attribute__((ext_vector_type(2)));
typedef float floatx16 __attribute__((ext_vector_type(16)));
typedef unsigned int uint4v __attribute__((ext_vector_type(4)));

union F8U { uint4v u; half8 h; };

#if __has_builtin(__builtin_amdgcn_exp2f)
#define EXP2F(x) __builtin_amdgcn_exp2f(x)
#else
#define EXP2F(x) exp2f(x)
#endif

static __device__ __forceinline__ unsigned pk2(float a, float b) {
#if __has_builtin(__builtin_amdgcn_cvt_pkrtz)
  fp16x2 h = __builtin_amdgcn_cvt_pkrtz(a, b);
  return __builtin_bit_cast(unsigned, h);
#else
  union { _Float16 h[2]; unsigned u; } r;
  r.h[0] = (_Float16)a; r.h[1] = (_Float16)b; return r.u;
#endif
}

__global__ __launch_bounds__(256, 1)
void ring_attn(const float* __restrict__ q, const float* __restrict__ k,
               const float* __restrict__ v, float* __restrict__ out)
{
  __shared__ _Float16 Kl[2][BN * KSTR];  // [n][d] fp16
  __shared__ _Float16 Vt[2][DH * VSTR];  // [d][n] fp16 (transposed)

  const int tid  = threadIdx.x;
  const int lane = tid & 63;
  const int wv   = tid >> 6;        // wave 0..3
  const int l31  = lane & 31;
  const int hb   = lane >> 5;       // half-wave 0/1
  const int b8   = hb * 8;
  const int batch = blockIdx.x & 31; // same-batch blocks land on one XCD (blk%8 const)
  const int qb    = blockIdx.x >> 5; // 0..7

  const float* kp = k + (size_t)batch * SKVL * DH;
  const float* vp = v + (size_t)batch * SKVL * DH;

  // ---- Q load: scale by log2(e), split hi+lo fp16; B-operand frags (col=m=l31, k=d) ----
  const float* qp = q + ((size_t)batch * SQL + qb * BM + wv * 32 + l31) * DH;
  half8 qhi[4], qlo[4];
#pragma unroll
  for (int kt = 0; kt < 4; ++kt) {
    float4 a = *(const float4*)(qp + kt * 16 + b8);
    float4 c = *(const float4*)(qp + kt * 16 + b8 + 4);
    float xs[8] = {a.x, a.y, a.z, a.w, c.x, c.y, c.z, c.w};
#pragma unroll
    for (int j = 0; j < 8; ++j) {
      float x = xs[j] * 1.44269504088896340736f;
      _Float16 h = (_Float16)x;       // RTN
      qhi[kt][j] = h;
      qlo[kt][j] = (_Float16)(x - (float)h);
    }
  }

  const int krt = tid >> 4;          // K stage: row base 0..15
  const int kc  = (tid & 15) * 4;    // K stage: d col
  const int vrp = tid >> 4;          // V stage: row-pair 0..15
  const int vc  = (tid & 15) * 4;    // V stage: d base

  float4 gk[4], gv0[2], gv1[2];
  // prefetch tile 0
#pragma unroll
  for (int it = 0; it < 4; ++it)
    gk[it] = *(const float4*)(kp + (size_t)(krt + it * 16) * DH + kc);
#pragma unroll
  for (int s = 0; s < 2; ++s) {
    int n = s * 32 + 2 * vrp;
    gv0[s] = *(const float4*)(vp + (size_t)n * DH + vc);
    gv1[s] = *(const float4*)(vp + (size_t)(n + 1) * DH + vc);
  }

  floatx16 accO[2];
#pragma unroll
  for (int i = 0; i < 2; ++i)
#pragma unroll
    for (int r = 0; r < 16; ++r) accO[i][r] = 0.f;
  float m_run = -3.0e38f, l_run = 0.f;

  int buf = 0;
  for (int tile = 0; tile < NT; ++tile) {
    _Float16* Kb = Kl[buf];
    _Float16* Vb = Vt[buf];

    // ---- stage prefetched regs -> LDS[buf] ----
#pragma unroll
    for (int it = 0; it < 4; ++it) {
      uint2 w2 = make_uint2(pk2(gk[it].x, gk[it].y), pk2(gk[it].z, gk[it].w));
      *(uint2*)&Kb[(krt + it * 16) * KSTR + kc] = w2;   // b64, ~2-way banks
    }
#pragma unroll
    for (int s = 0; s < 2; ++s) {
      int n = s * 32 + 2 * vrp;
      float a0[4] = {gv0[s].x, gv0[s].y, gv0[s].z, gv0[s].w};
      float a1[4] = {gv1[s].x, gv1[s].y, gv1[s].z, gv1[s].w};
#pragma unroll
      for (int i = 0; i < 4; ++i)     // transposed pair-packed b32: conflict-free banks
        *(unsigned*)&Vb[(vc + i) * VSTR + n] = pk2(a0[i], a1[i]);
    }
    __syncthreads();   // single barrier per tile (double buffer makes it sufficient)

    // ---- prefetch next tile into regs (latency hidden behind compute) ----
    if (tile + 1 < NT) {
      const float* kn = kp + (size_t)(tile + 1) * BN * DH;
      const float* vn = vp + (size_t)(tile + 1) * BN * DH;
#pragma unroll
      for (int it = 0; it < 4; ++it)
        gk[it] = *(const float4*)(kn + (size_t)(krt + it * 16) * DH + kc);
#pragma unroll
      for (int s = 0; s < 2; ++s) {
        int n = s * 32 + 2 * vrp;
        gv0[s] = *(const float4*)(vn + (size_t)n * DH + vc);
        gv1[s] = *(const float4*)(vn + (size_t)(n + 1) * DH + vc);
      }
    }

    // ---- S^T = K_tile · Q^T : rows n (2 subtiles of 32), cols m ----
    floatx16 st[2];
#pragma unroll
    for (int t = 0; t < 2; ++t)
#pragma unroll
      for (int r = 0; r < 16; ++r) st[t][r] = 0.f;
#pragma unroll
    for (int kt = 0; kt < 4; ++kt) {
#pragma unroll
      for (int t = 0; t < 2; ++t) {
        half8 kf = *(const half8*)&Kb[(t * 32 + l31) * KSTR + kt * 16 + b8];
        st[t] = __builtin_amdgcn_mfma_f32_32x32x16_f16(kf, qhi[kt], st[t], 0, 0, 0);
        st[t] = __builtin_amdgcn_mfma_f32_32x32x16_f16(kf, qlo[kt], st[t], 0, 0, 0);
      }
    }

    // ---- online softmax: lane owns q-row m=l31; halves hold complementary n ----
    float mx = -3.0e38f;
#pragma unroll
    for (int t = 0; t < 2; ++t)
#pragma unroll
      for (int r = 0; r < 16; ++r) mx = fmaxf(mx, st[t][r]);
    mx = fmaxf(mx, __shfl_xor(mx, 32, 64));
    float m_new = fmaxf(m_run, mx);
    float alpha = EXP2F(m_run - m_new);
    m_run = m_new;
    float sum = 0.f;
#pragma unroll
    for (int t = 0; t < 2; ++t)
#pragma unroll
      for (int r = 0; r < 16; ++r) {
        float p = EXP2F(st[t][r] - m_new);
        st[t][r] = p;
        sum += p;
      }
    sum += __shfl_xor(sum, 32, 64);
    l_run = alpha * l_run + sum;

    // rescale O accumulator rows by alpha of that row (shfl broadcast)
#pragma unroll
    for (int r = 0; r < 16; ++r) {
      int row = (r & 3) + 8 * (r >> 2) + 4 * hb;
      float ar = __shfl(alpha, row, 64);
      accO[0][r] *= ar;
      accO[1][r] *= ar;
    }

    // ---- P·V: build A-frags of P via cross-half exchange, B = V^T from LDS ----
#pragma unroll
    for (int t = 0; t < 2; ++t) {
      unsigned P01 = pk2(st[t][0],  st[t][1]);
      unsigned P23 = pk2(st[t][2],  st[t][3]);
      unsigned P45 = pk2(st[t][4],  st[t][5]);
      unsigned P67 = pk2(st[t][6],  st[t][7]);
      unsigned P89 = pk2(st[t][8],  st[t][9]);
      unsigned PAB = pk2(st[t][10], st[t][11]);
      unsigned PCD = pk2(st[t][12], st[t][13]);
      unsigned PEF = pk2(st[t][14], st[t][15]);
      unsigned x01 = __shfl_xor(P01, 32, 64), x23 = __shfl_xor(P23, 32, 64);
      unsigned x45 = __shfl_xor(P45, 32, 64), x67 = __shfl_xor(P67, 32, 64);
      unsigned x89 = __shfl_xor(P89, 32, 64), xAB = __shfl_xor(PAB, 32, 64);
      unsigned xCD = __shfl_xor(PCD, 32, 64), xEF = __shfl_xor(PEF, 32, 64);
      F8U fe, fo;
      fe.u = uint4v{hb ? x45 : P01, hb ? x67 : P23, hb ? P45 : x01, hb ? P67 : x23};
      fo.u = uint4v{hb ? xCD : P89, hb ? xEF : PAB, hb ? PCD : x89, hb ? PEF : xAB};
#pragma unroll
      for (int ds = 0; ds < 2; ++ds) {
        half8 vf0 = *(const half8*)&Vb[(ds * 32 + l31) * VSTR + (2 * t) * 16 + b8];
        accO[ds] = __builtin_amdgcn_mfma_f32_32x32x16_f16(fe.h, vf0, accO[ds], 0, 0, 0);
        half8 vf1 = *(const half8*)&Vb[(ds * 32 + l31) * VSTR + (2 * t + 1) * 16 + b8];
        accO[ds] = __builtin_amdgcn_mfma_f32_32x32x16_f16(fo.h, vf1, accO[ds], 0, 0, 0);
      }
    }
    buf ^= 1;
  }

  // ---- epilogue: divide by l (row-broadcast), coalesced f32 stores ----
  float linv = 1.0f / l_run;
  float* op = out + ((size_t)batch * SQL + qb * BM + wv * 32) * DH;
#pragma unroll
  for (int r = 0; r < 16; ++r) {
    int row = (r & 3) + 8 * (r >> 2) + 4 * hb;
    float lr = __shfl(linv, row, 64);
    op[(size_t)row * DH + l31]      = accO[0][r] * lr;
    op[(size_t)row * DH + 32 + l31] = accO[1][r] * lr;
  }
}

extern "C" void kernel_launch(void* const* d_in, const int* in_sizes, int n_in,
                              void* d_out, int out_size, void* d_ws, size_t ws_size,
                              hipStream_t stream) {
  (void)in_sizes; (void)n_in; (void)d_ws; (void)ws_size; (void)out_size;
  const float* q = (const float*)d_in[0];
  const float* k = (const float*)d_in[1];
  const float* v = (const float*)d_in[2];
  ring_attn<<<dim3(NBATCH * (SQL / BM)), dim3(256), 0, stream>>>(q, k, v, (float*)d_out);
}